// Round 1
// 2784.506 us; speedup vs baseline: 1.4121x; 1.4121x over previous
//
#include <hip/hip_runtime.h>
#include <stdint.h>

#define DI __device__ __forceinline__

typedef short s16x8 __attribute__((ext_vector_type(8)));
typedef float f32x4 __attribute__((ext_vector_type(4)));

// ---- constants ----
#define NG   2048
#define NP   512
#define TT   100
#define BB   256
#define N4   8192   // 4*NG
#define MR   25600  // B*T

DI unsigned short f32_to_bf16(float f) {
  union { float f; uint32_t u; } x; x.f = f;
  uint32_t r = x.u + 0x7fffu + ((x.u >> 16) & 1u);
  return (unsigned short)(r >> 16);
}

DI void async16(const void* g, void* l) {
  __builtin_amdgcn_global_load_lds((const __attribute__((address_space(1))) void*)g,
                                   (__attribute__((address_space(3))) void*)l,
                                   16, 0, 0);
}

DI f32x4 mfma16(s16x8 a, s16x8 b, f32x4 c) {
  return __builtin_amdgcn_mfma_f32_16x16x32_bf16(a, b, c, 0, 0, 0);
}

// =====================================================================
// Pipelined bf16 MFMA core: BM x 128 tile, BK=64, 512 threads (8 waves
// as 2x4), double-buffered LDS, prefetch-next-before-compute (T3 minimum
// 2-phase), XOR-swizzled LDS to kill ds_read_b128 bank conflicts (T2,
// rule 21: linear LDS dest + inverse-swizzled global source col).
// A row-major [M][K] bf16, Bt n-major [N][K] bf16.
// acc layout: acc[fm*2+fn], FM = BM/32, FN = 2.
// Wave (wm = wave>>2, wn = wave&3) owns rows [wm*BM/2, +BM/2),
// cols [wn*32, +32).
// sA: 2*BM*64 shorts. sB: 2*128*64 shorts.
// =====================================================================
template <int BM>
DI void gemm_core_p(const unsigned short* __restrict__ A, int lda, int m0,
                    const unsigned short* __restrict__ Bt, int ldb, int n0, int K,
                    unsigned short* sA, unsigned short* sB, f32x4* acc) {
  constexpr int FM = BM / 32;
  const int tid  = threadIdx.x;
  const int wave = tid >> 6;
  const int lane = tid & 63;
  const int quad = lane >> 4;
  const int lr   = lane & 15;
  const int wm   = wave >> 2;
  const int wn   = wave & 3;
  const int lr8  = lane >> 3;              // row within 8-row chunk
  const int lc8  = lane & 7;               // 16B column chunk
  const int scol = (lc8 ^ lr8) << 3;       // inverse-swizzled source col (shorts)

  const int nkt = K >> 6;
  int buf = 0;

  auto stage = [&](int bsel, int k0) {
    unsigned short* dA = sA + bsel * (BM * 64);
    unsigned short* dB = sB + bsel * (128 * 64);
#pragma unroll
    for (int c = 0; c < BM / 64; ++c) {
      int rbase = wave * (BM / 8) + c * 8;
      const unsigned short* g = A + (size_t)(m0 + rbase + lr8) * lda + (k0 + scol);
      async16(g, dA + rbase * 64);         // wave-uniform LDS base; HW adds lane*16
    }
#pragma unroll
    for (int c = 0; c < 2; ++c) {
      int rbase = wave * 16 + c * 8;
      const unsigned short* g = Bt + (size_t)(n0 + rbase + lr8) * ldb + (k0 + scol);
      async16(g, dB + rbase * 64);
    }
  };

  stage(0, 0);
  __syncthreads();                          // drains vmcnt -> buf0 ready
  for (int kt = 0; kt < nkt; ++kt) {
    if (kt + 1 < nkt) stage(buf ^ 1, (kt + 1) << 6);   // prefetch next tile
    const char* cA = (const char*)(sA + buf * (BM * 64));
    const char* cB = (const char*)(sB + buf * (128 * 64));
#pragma unroll
    for (int ks = 0; ks < 2; ++ks) {
      s16x8 af[FM], bfr[2];
#pragma unroll
      for (int fm = 0; fm < FM; ++fm) {
        int row = wm * (BM / 2) + fm * 16 + lr;
        int off = row * 128 + ((ks * 64 + quad * 16) ^ ((row & 7) << 4));
        af[fm] = *(const s16x8*)(cA + off);
      }
#pragma unroll
      for (int fn = 0; fn < 2; ++fn) {
        int col = wn * 32 + fn * 16 + lr;
        int off = col * 128 + ((ks * 64 + quad * 16) ^ ((col & 7) << 4));
        bfr[fn] = *(const s16x8*)(cB + off);
      }
#pragma unroll
      for (int fm = 0; fm < FM; ++fm)
#pragma unroll
        for (int fn = 0; fn < 2; ++fn)
          acc[fm * 2 + fn] = mfma16(af[fm], bfr[fn], acc[fm * 2 + fn]);
    }
    __syncthreads();   // one barrier/iter: drains this iter's prefetch too
    buf ^= 1;
  }
}

// =====================================================================
// Transpose + fp32->bf16 convert. src fp32 [R][C] row-major ->
// dst bf16 [n(C)][R] row-major. MODE 0: n = c + noff. MODE 1 (lstm_U gate
// interleave): n = (c & 2047)*4 + (c >> 11).
// =====================================================================
template <int MODE>
__global__ __launch_bounds__(256) void k_transpose_bf16(
    const float* __restrict__ src, unsigned short* __restrict__ dst,
    int R, int C, int noff) {
  __shared__ unsigned short tile[64][65];
  int tr0 = blockIdx.x * 64;
  int tc0 = blockIdx.y * 64;
  int tid = threadIdx.x;
#pragma unroll
  for (int i = 0; i < 16; ++i) {
    int idx = tid + i * 256;
    int r = idx >> 6, c = idx & 63;
    tile[r][c] = f32_to_bf16(src[(size_t)(tr0 + r) * C + (tc0 + c)]);
  }
  __syncthreads();
#pragma unroll
  for (int i = 0; i < 16; ++i) {
    int idx = tid + i * 256;
    int cc = idx >> 6, r = idx & 63;
    int c = tc0 + cc;
    int n = (MODE == 0) ? (c + noff) : (((c & 2047) << 2) | (c >> 11));
    dst[(size_t)n * R + (tr0 + r)] = tile[r][cc];
  }
}

__global__ __launch_bounds__(256) void k_cvt(const float* __restrict__ src,
                                             unsigned short* __restrict__ dst, int n) {
  int i = blockIdx.x * 256 + threadIdx.x;
  if (i < n) dst[i] = f32_to_bf16(src[i]);
}

// ---- W2 = M_W @ lstm_W, bias2 = M_b @ lstm_W + lstm_b (gate-reordered) ----
__global__ __launch_bounds__(256) void k_prep_xw_part(
    const float* __restrict__ lstm_W, const float* __restrict__ M_W,
    const float* __restrict__ M_b, float* __restrict__ part) {
  int c = blockIdx.x * 256 + threadIdx.x;   // 0..8191 original column
  int kc = blockIdx.y;
  int k0 = kc * 128;
  float a0 = 0.f, a1 = 0.f, ab = 0.f;
  for (int k = k0; k < k0 + 128; ++k) {
    float w = lstm_W[(size_t)k * N4 + c];
    a0 += M_W[k] * w;
    a1 += M_W[NG + k] * w;
    ab += M_b[k] * w;
  }
  float* p = part + (size_t)kc * 3 * N4;
  p[c] = a0; p[N4 + c] = a1; p[2 * N4 + c] = ab;
}

__global__ __launch_bounds__(256) void k_prep_xw_reduce(
    const float* __restrict__ part, const float* __restrict__ lstm_b,
    float* __restrict__ W2r, float* __restrict__ b2r) {
  int c = blockIdx.x * 256 + threadIdx.x;
  float a0 = 0.f, a1 = 0.f, ab = 0.f;
  for (int kc = 0; kc < 16; ++kc) {
    const float* p = part + (size_t)kc * 3 * N4;
    a0 += p[c]; a1 += p[N4 + c]; ab += p[2 * N4 + c];
  }
  int n = ((c & 2047) << 2) | (c >> 11);   // gate interleave
  W2r[n] = a0; W2r[N4 + n] = a1; b2r[n] = ab + lstm_b[c];
}

// ---- encoders: [h0 | c0] = p0 @ [enc1_W ; enc2_W] packed as N=4096 ----
__global__ __launch_bounds__(512) void k_enc(
    const unsigned short* __restrict__ p0b, const unsigned short* __restrict__ encWt,
    const float* __restrict__ enc1_b, const float* __restrict__ enc2_b,
    unsigned short* __restrict__ hbf, float* __restrict__ cfp) {
  __shared__ __align__(16) unsigned short sA[2 * 64 * 64];
  __shared__ __align__(16) unsigned short sB[2 * 128 * 64];
  int m0 = blockIdx.x * 64, n0 = blockIdx.y * 128;
  const f32x4 vzero = {0.f, 0.f, 0.f, 0.f};
  f32x4 acc[4];
#pragma unroll
  for (int i = 0; i < 4; ++i) acc[i] = vzero;
  gemm_core_p<64>(p0b, NP, m0, encWt, NP, n0, NP, sA, sB, acc);

  const int tid = threadIdx.x, wave = tid >> 6, lane = tid & 63;
  const int quad = lane >> 4, lr = lane & 15, wm = wave >> 2, wn = wave & 3;
#pragma unroll
  for (int fm = 0; fm < 2; ++fm)
#pragma unroll
    for (int fn = 0; fn < 2; ++fn)
#pragma unroll
      for (int reg = 0; reg < 4; ++reg) {
        int grow = m0 + wm * 32 + fm * 16 + quad * 4 + reg;
        int gcol = n0 + wn * 32 + fn * 16 + lr;
        float val = acc[fm * 2 + fn][reg];
        if (gcol < NG)
          hbf[(size_t)grow * NG + gcol] = f32_to_bf16(val + enc1_b[gcol]);
        else
          cfp[(size_t)grow * NG + (gcol - NG)] = val + enc2_b[gcol - NG];
      }
}

// ---- one LSTM step: z = h@Ut + rank2(v_t) + bias2, fused gate update ----
// 256 blocks (4 mt x 64 nt, XCD swizzle), 512 threads, tile 64x128.
__global__ __launch_bounds__(512) void k_step(
    const unsigned short* __restrict__ hin, const unsigned short* __restrict__ Ut,
    const float* __restrict__ vv, const float* __restrict__ W2r,
    const float* __restrict__ b2r, float* __restrict__ cfp,
    unsigned short* __restrict__ hout, unsigned short* __restrict__ hs, int t) {
  // staging: sA 2*64*64 shorts (16KB) + sB 2*128*64 shorts (32KB) = 48KB,
  // reused as z [64][132] f32 (33.8KB) in the epilogue.
  __shared__ __align__(16) char smem[49152];
  unsigned short* sA = (unsigned short*)smem;
  unsigned short* sB = (unsigned short*)(smem + 16384);

  int bid = blockIdx.x;                 // XCD-aware swizzle keeps Ut panel L2-resident
  int xcd = bid & 7, s = bid >> 3;
  int mt = s >> 3, nsub = s & 7;
  int nt = xcd * 8 + nsub;
  int m0 = mt * 64, n0 = nt * 128;
  int tid = threadIdx.x;

  const f32x4 vzero = {0.f, 0.f, 0.f, 0.f};
  f32x4 acc[4];
#pragma unroll
  for (int i = 0; i < 4; ++i) acc[i] = vzero;
  gemm_core_p<64>(hin, NG, m0, Ut, NG, n0, NG, sA, sB, acc);

  const int wave = tid >> 6, lane = tid & 63;
  const int quad = lane >> 4, lr = lane & 15, wm = wave >> 2, wn = wave & 3;
  // phase 1: z -> LDS (reuse staging; safe after final in-loop barrier)
  float* zs = (float*)smem;
#pragma unroll
  for (int fm = 0; fm < 2; ++fm)
#pragma unroll
    for (int fn = 0; fn < 2; ++fn)
#pragma unroll
      for (int reg = 0; reg < 4; ++reg) {
        int r  = wm * 32 + fm * 16 + quad * 4 + reg;
        int cc = wn * 32 + fn * 16 + lr;
        zs[r * 132 + cc] = acc[fm * 2 + fn][reg];
      }
  __syncthreads();
  // phase 2: gate update, 64 rows x 32 cells, input term fused here.
  // j = tid&31 is constant per thread -> W2/b2 float4 in registers.
  const int j = tid & 31;
  const int gbase = n0 + 4 * j;
  const float4 w2a = *(const float4*)(W2r + gbase);
  const float4 w2b = *(const float4*)(W2r + N4 + gbase);
  const float4 bb  = *(const float4*)(b2r + gbase);
  const int cell = (n0 >> 2) + j;
#pragma unroll
  for (int i = 0; i < 4; ++i) {
    int r = (tid >> 5) + i * 16;
    int b = m0 + r;
    const float2 vb = *(const float2*)(vv + ((size_t)b * TT + t) * 2);
    float4 z4 = *(const float4*)(zs + r * 132 + 4 * j);
    float zi = z4.x + vb.x * w2a.x + vb.y * w2b.x + bb.x;
    float zf = z4.y + vb.x * w2a.y + vb.y * w2b.y + bb.y;
    float zg = z4.z + vb.x * w2a.z + vb.y * w2b.z + bb.z;
    float zo = z4.w + vb.x * w2a.w + vb.y * w2b.w + bb.w;
    float i_ = 1.f / (1.f + __expf(-zi));
    float f_ = 1.f / (1.f + __expf(-zf));
    float g_ = fmaxf(zg, 0.f);
    float o_ = 1.f / (1.f + __expf(-zo));
    size_t ci = (size_t)b * NG + cell;
    float cn = f_ * cfp[ci] + i_ * g_;
    cfp[ci] = cn;
    unsigned short hb = f32_to_bf16(o_ * fmaxf(cn, 0.f));
    hout[ci] = hb;
    hs[((size_t)t * BB + b) * NG + cell] = hb;
  }
}

// ---- g_cells = relu(hs @ dense_W + dense_b) -> bf16 ----
__global__ __launch_bounds__(512) void k_dense(
    const unsigned short* __restrict__ hs, const unsigned short* __restrict__ dWt,
    const float* __restrict__ dense_b, unsigned short* __restrict__ gc) {
  __shared__ __align__(16) unsigned short sA[2 * 128 * 64];
  __shared__ __align__(16) unsigned short sB[2 * 128 * 64];
  int m0 = blockIdx.x * 128, n0 = blockIdx.y * 128;
  const f32x4 vzero = {0.f, 0.f, 0.f, 0.f};
  f32x4 acc[8];
#pragma unroll
  for (int i = 0; i < 8; ++i) acc[i] = vzero;
  gemm_core_p<128>(hs, NG, m0, dWt, NG, n0, NG, sA, sB, acc);

  const int tid = threadIdx.x, wave = tid >> 6, lane = tid & 63;
  const int quad = lane >> 4, lr = lane & 15, wm = wave >> 2, wn = wave & 3;
#pragma unroll
  for (int fm = 0; fm < 4; ++fm)
#pragma unroll
    for (int fn = 0; fn < 2; ++fn)
#pragma unroll
      for (int reg = 0; reg < 4; ++reg) {
        int grow = m0 + wm * 64 + fm * 16 + quad * 4 + reg;
        int gcol = n0 + wn * 32 + fn * 16 + lr;
        float val = fmaxf(acc[fm * 2 + fn][reg] + dense_b[gcol], 0.f);
        gc[(size_t)grow * NG + gcol] = f32_to_bf16(val);
      }
}

// ---- place_preds = g_cells @ dec_W + dec_b (fp32 out, [B][T][Np]) ----
__global__ __launch_bounds__(512) void k_dec(
    const unsigned short* __restrict__ gc, const unsigned short* __restrict__ decWt,
    const float* __restrict__ dec_b, float* __restrict__ out) {
  __shared__ __align__(16) unsigned short sA[2 * 128 * 64];
  __shared__ __align__(16) unsigned short sB[2 * 128 * 64];
  int m0 = blockIdx.x * 128, n0 = blockIdx.y * 128;
  const f32x4 vzero = {0.f, 0.f, 0.f, 0.f};
  f32x4 acc[8];
#pragma unroll
  for (int i = 0; i < 8; ++i) acc[i] = vzero;
  gemm_core_p<128>(gc, NG, m0, decWt, NG, n0, NG, sA, sB, acc);

  const int tid = threadIdx.x, wave = tid >> 6, lane = tid & 63;
  const int quad = lane >> 4, lr = lane & 15, wm = wave >> 2, wn = wave & 3;
#pragma unroll
  for (int fm = 0; fm < 4; ++fm)
#pragma unroll
    for (int fn = 0; fn < 2; ++fn)
#pragma unroll
      for (int reg = 0; reg < 4; ++reg) {
        int grow = m0 + wm * 64 + fm * 16 + quad * 4 + reg;   // t*256+b
        int gcol = n0 + wn * 32 + fn * 16 + lr;               // 0..511
        int tt = grow >> 8, b = grow & 255;
        out[((size_t)b * TT + tt) * NP + gcol] = acc[fm * 2 + fn][reg] + dec_b[gcol];
      }
}

// =====================================================================
extern "C" void kernel_launch(void* const* d_in, const int* in_sizes, int n_in,
                              void* d_out, int out_size, void* d_ws, size_t ws_size,
                              hipStream_t stream) {
  (void)in_sizes; (void)n_in; (void)out_size; (void)ws_size;
  const float* v       = (const float*)d_in[0];
  const float* p0      = (const float*)d_in[1];
  const float* enc1_W  = (const float*)d_in[2];
  const float* enc1_b  = (const float*)d_in[3];
  const float* enc2_W  = (const float*)d_in[4];
  const float* enc2_b  = (const float*)d_in[5];
  const float* M_W     = (const float*)d_in[6];
  const float* M_b     = (const float*)d_in[7];
  const float* lstm_W  = (const float*)d_in[8];
  const float* lstm_U  = (const float*)d_in[9];
  const float* lstm_b  = (const float*)d_in[10];
  const float* dense_W = (const float*)d_in[11];
  const float* dense_b = (const float*)d_in[12];
  const float* dec_W   = (const float*)d_in[13];
  const float* dec_b   = (const float*)d_in[14];
  float* out = (float*)d_out;

  char* ws = (char*)d_ws;
  size_t off = 0;
  auto alloc = [&](size_t bytes) {
    char* p = ws + off;
    off += (bytes + 255) & ~(size_t)255;
    return p;
  };
  unsigned short* Ut    = (unsigned short*)alloc((size_t)N4 * NG * 2);   // 32 MB
  unsigned short* dWt   = (unsigned short*)alloc((size_t)NG * NG * 2);   // 8 MB
  unsigned short* decWt = (unsigned short*)alloc((size_t)NP * NG * 2);   // 2 MB
  unsigned short* encWt = (unsigned short*)alloc((size_t)2 * NG * NP * 2);
  unsigned short* p0b   = (unsigned short*)alloc((size_t)BB * NP * 2);
  float* W2r  = (float*)alloc((size_t)2 * N4 * 4);
  float* b2r  = (float*)alloc((size_t)N4 * 4);
  float* part = (float*)alloc((size_t)16 * 3 * N4 * 4);
  float* cfp  = (float*)alloc((size_t)BB * NG * 4);
  unsigned short* hb0 = (unsigned short*)alloc((size_t)BB * NG * 2);
  unsigned short* hb1 = (unsigned short*)alloc((size_t)BB * NG * 2);
  unsigned short* hs  = (unsigned short*)alloc((size_t)MR * NG * 2);     // 100 MB
  unsigned short* gc  = (unsigned short*)alloc((size_t)MR * NG * 2);     // 100 MB

  dim3 blk(256), blk5(512);
  // weight conversion / transposes
  k_transpose_bf16<1><<<dim3(32, 128), blk, 0, stream>>>(lstm_U, Ut, NG, N4, 0);
  k_transpose_bf16<0><<<dim3(32, 32), blk, 0, stream>>>(dense_W, dWt, NG, NG, 0);
  k_transpose_bf16<0><<<dim3(32, 8), blk, 0, stream>>>(dec_W, decWt, NG, NP, 0);
  k_transpose_bf16<0><<<dim3(8, 32), blk, 0, stream>>>(enc1_W, encWt, NP, NG, 0);
  k_transpose_bf16<0><<<dim3(8, 32), blk, 0, stream>>>(enc2_W, encWt, NP, NG, NG);
  k_cvt<<<dim3(512), blk, 0, stream>>>(p0, p0b, BB * NP);
  // rank-2 collapse of input path
  k_prep_xw_part<<<dim3(32, 16), blk, 0, stream>>>(lstm_W, M_W, M_b, part);
  k_prep_xw_reduce<<<dim3(32), blk, 0, stream>>>(part, lstm_b, W2r, b2r);
  // initial state
  k_enc<<<dim3(4, 32), blk5, 0, stream>>>(p0b, encWt, enc1_b, enc2_b, hb0, cfp);
  // recurrence
  for (int t = 0; t < TT; ++t) {
    const unsigned short* hin = (t & 1) ? hb1 : hb0;
    unsigned short* hout      = (t & 1) ? hb0 : hb1;
    k_step<<<dim3(256), blk5, 0, stream>>>(hin, Ut, v, W2r, b2r, cfp, hout, hs, t);
  }
  // readout
  k_dense<<<dim3(200, 16), blk5, 0, stream>>>(hs, dWt, dense_b, gc);
  k_dec<<<dim3(200, 4), blk5, 0, stream>>>(gc, decWt, dec_b, out);
}